// Round 1
// baseline (709.424 us; speedup 1.0000x reference)
//
#include <hip/hip_runtime.h>
#include <math.h>

#define BB 4
#define HH 128
#define WW 128
#define CIN 64
#define COUT 64
#define KK 9
#define OMC 27
#define NPIX (BB * HH * WW)

// ---------------------------------------------------------------------------
// Kernel 1: offset/mask conv.  om[pix][j] = bias[j] + sum_{t,c} x[nbr(t)][c] * wofs[t][c][j]
// One thread per (pixel, j).  j = tid % 27 -> wofs reads coalesced over j;
// x reads are identical across the 27 lanes of a pixel -> merged/broadcast.
// ---------------------------------------------------------------------------
__global__ __launch_bounds__(256) void offset_conv_kernel(
    const float* __restrict__ x,
    const float* __restrict__ wofs,
    const float* __restrict__ bofs,
    float* __restrict__ om)
{
    int tid = blockIdx.x * 256 + threadIdx.x;
    if (tid >= NPIX * OMC) return;
    int j   = tid % OMC;
    int pix = tid / OMC;
    int w = pix & (WW - 1);
    int h = (pix >> 7) & (HH - 1);
    int b = pix >> 14;

    float acc = bofs[j];
    const float* xb = x + (size_t)b * HH * WW * CIN;

    #pragma unroll
    for (int t = 0; t < KK; ++t) {
        int y  = h - 1 + (t / 3);
        int xx = w - 1 + (t % 3);
        if (y < 0 || y >= HH || xx < 0 || xx >= WW) continue;
        const float* xp = xb + ((size_t)y * WW + xx) * CIN;
        const float* wp = wofs + (size_t)t * CIN * OMC + j;
        #pragma unroll 4
        for (int c = 0; c < CIN; c += 4) {
            const float4 xv = *reinterpret_cast<const float4*>(xp + c);
            acc = fmaf(xv.x, wp[(c + 0) * OMC], acc);
            acc = fmaf(xv.y, wp[(c + 1) * OMC], acc);
            acc = fmaf(xv.z, wp[(c + 2) * OMC], acc);
            acc = fmaf(xv.w, wp[(c + 3) * OMC], acc);
        }
    }
    om[tid] = acc;
}

// ---------------------------------------------------------------------------
// Kernel 2: deformable sampling + 576->64 contraction.
// Block = 128 threads = 2 waves; each wave owns PPW=8 pixels.
// Phase 1: lane = cin.  For each (pixel, tap): read offsets/mask, bilinear
//          gather 4 corners (coalesced 256B per corner), write s*mask to LDS.
// Phase 2: lane = cout.  acc[p] += s[p][tc] (LDS float4 broadcast) * w[tc][lane]
//          (coalesced from L2; 147 KB per wave amortized over 8 pixels).
// ---------------------------------------------------------------------------
#define PPW 8
#define WAVES 2

__global__ __launch_bounds__(WAVES * 64) void dcn_main_kernel(
    const float* __restrict__ x,
    const float* __restrict__ wmain,   // [9][64][64] = [tc][o]
    const float* __restrict__ bias,
    const float* __restrict__ om,
    float* __restrict__ out)
{
    __shared__ float s_s[WAVES * PPW * KK * CIN];  // 2*8*9*64*4 = 36864 B

    const int lane = threadIdx.x & 63;
    const int wv   = threadIdx.x >> 6;
    const int pix0 = (blockIdx.x * WAVES + wv) * PPW;
    float* sbase = s_s + wv * (PPW * KK * CIN);

    // ---- phase 1: sampling (lane = cin) ----
    for (int p = 0; p < PPW; ++p) {
        const int pix = pix0 + p;
        const int w = pix & (WW - 1);
        const int h = (pix >> 7) & (HH - 1);
        const int b = pix >> 14;
        const float* omp = om + (size_t)pix * OMC;
        const float* xb  = x + (size_t)b * HH * WW * CIN;

        #pragma unroll
        for (int t = 0; t < KK; ++t) {
            const float dy = omp[2 * t];
            const float dx = omp[2 * t + 1];
            float mk = omp[18 + t];
            mk = 1.0f / (1.0f + expf(-mk));

            const float py = (float)(h - 1 + (t / 3)) + dy;
            const float px = (float)(w - 1 + (t % 3)) + dx;
            const float fy = floorf(py), fx = floorf(px);
            const int y0 = (int)fy, x0 = (int)fx;
            const float wy1 = py - fy, wx1 = px - fx;
            const float wy0 = 1.0f - wy1, wx0 = 1.0f - wx1;

            float v = 0.0f;
            if (y0 >= 0 && y0 < HH) {
                const float* row = xb + (size_t)y0 * WW * CIN;
                if (x0 >= 0 && x0 < WW)
                    v = fmaf(wy0 * wx0, row[(size_t)x0 * CIN + lane], v);
                if (x0 + 1 >= 0 && x0 + 1 < WW)
                    v = fmaf(wy0 * wx1, row[(size_t)(x0 + 1) * CIN + lane], v);
            }
            if (y0 + 1 >= 0 && y0 + 1 < HH) {
                const float* row = xb + (size_t)(y0 + 1) * WW * CIN;
                if (x0 >= 0 && x0 < WW)
                    v = fmaf(wy1 * wx0, row[(size_t)x0 * CIN + lane], v);
                if (x0 + 1 >= 0 && x0 + 1 < WW)
                    v = fmaf(wy1 * wx1, row[(size_t)(x0 + 1) * CIN + lane], v);
            }
            sbase[(p * KK + t) * CIN + lane] = v * mk;
        }
    }
    __syncthreads();

    // ---- phase 2: contraction (lane = cout) ----
    float acc[PPW];
    const float bs = bias[lane];
    #pragma unroll
    for (int p = 0; p < PPW; ++p) acc[p] = bs;

    for (int tc = 0; tc < KK * CIN; tc += 4) {
        const float w0 = wmain[(size_t)(tc + 0) * COUT + lane];
        const float w1 = wmain[(size_t)(tc + 1) * COUT + lane];
        const float w2 = wmain[(size_t)(tc + 2) * COUT + lane];
        const float w3 = wmain[(size_t)(tc + 3) * COUT + lane];
        #pragma unroll
        for (int p = 0; p < PPW; ++p) {
            const float4 sv = *reinterpret_cast<const float4*>(&sbase[p * (KK * CIN) + tc]);
            acc[p] = fmaf(sv.x, w0, acc[p]);
            acc[p] = fmaf(sv.y, w1, acc[p]);
            acc[p] = fmaf(sv.z, w2, acc[p]);
            acc[p] = fmaf(sv.w, w3, acc[p]);
        }
    }

    #pragma unroll
    for (int p = 0; p < PPW; ++p)
        out[(size_t)(pix0 + p) * COUT + lane] = acc[p];
}

extern "C" void kernel_launch(void* const* d_in, const int* in_sizes, int n_in,
                              void* d_out, int out_size, void* d_ws, size_t ws_size,
                              hipStream_t stream)
{
    const float* x     = (const float*)d_in[0];
    const float* wmain = (const float*)d_in[1];
    const float* bias  = (const float*)d_in[2];
    const float* wofs  = (const float*)d_in[3];
    const float* bofs  = (const float*)d_in[4];
    float* out = (float*)d_out;
    float* om  = (float*)d_ws;  // NPIX * 27 * 4 B = 6.75 MB

    {
        const int total = NPIX * OMC;
        const int blocks = (total + 255) / 256;
        offset_conv_kernel<<<blocks, 256, 0, stream>>>(x, wofs, bofs, om);
    }
    {
        const int blocks = NPIX / (WAVES * PPW);  // 65536 / 16 = 4096
        dcn_main_kernel<<<blocks, WAVES * 64, 0, stream>>>(x, wmain, bias, om, out);
    }
}

// Round 2
// 348.058 us; speedup vs baseline: 2.0382x; 2.0382x over previous
//
#include <hip/hip_runtime.h>
#include <math.h>

#define BB 4
#define HH 128
#define WW 128
#define CIN 64
#define COUT 64
#define KK 9
#define OMC 27
#define NPIX (BB * HH * WW)

typedef __attribute__((ext_vector_type(8))) short bf16x8;
typedef __attribute__((ext_vector_type(4))) float f32x4;

static __device__ __forceinline__ unsigned short f2bf(float f) {
    unsigned int u = __float_as_uint(f);
    unsigned int r = (u + 0x7fffu + ((u >> 16) & 1u)) >> 16;
    return (unsigned short)r;
}

// ---------------------------------------------------------------------------
// Kernel 1: offset/mask conv as bf16 MFMA implicit GEMM.
// One block per (b, h) image row: M = 128 pixels (w), N = 32 (27 j padded),
// K = 576 (9 taps x 64 cin).  x row and wofs staged in LDS as bf16 with
// XOR swizzle (byte ^= (row&7)<<4) to kill stride-128B bank conflicts.
// 4 waves: wave wv owns pixels [32wv, 32wv+32) -> acc frags [2 M][2 N].
// ---------------------------------------------------------------------------
__global__ __launch_bounds__(256) void offset_conv_mfma(
    const float* __restrict__ x,
    const float* __restrict__ wofs,
    const float* __restrict__ bofs,
    float* __restrict__ om)
{
    // xs: [128 w][64 c] bf16 = 16384 B ; ws: [9 t][32 j][64 c] bf16 = 36864 B
    __shared__ char lds[16384 + 36864];
    char* xs = lds;
    char* ws = lds + 16384;

    const int tid  = threadIdx.x;
    const int lane = tid & 63;
    const int wv   = tid >> 6;
    const int b = blockIdx.x >> 7;
    const int h = blockIdx.x & (HH - 1);
    const float* xrow0 = x + (size_t)b * HH * WW * CIN;

    // ---- stage wofs -> ws[t][j][c] bf16, swizzled, zero-pad j>=27 ----
    #pragma unroll
    for (int r = 0; r < 9; ++r) {
        const int t  = r;
        const int j  = (tid >> 3) & 31;
        const int c8 = tid & 7;
        unsigned short v[8];
        if (j < OMC) {
            const float* wp = wofs + ((size_t)t * CIN + c8 * 8) * OMC + j;
            #pragma unroll
            for (int i = 0; i < 8; ++i) v[i] = f2bf(wp[i * OMC]);
        } else {
            #pragma unroll
            for (int i = 0; i < 8; ++i) v[i] = 0;
        }
        uint4 q;
        q.x = (unsigned int)v[0] | ((unsigned int)v[1] << 16);
        q.y = (unsigned int)v[2] | ((unsigned int)v[3] << 16);
        q.z = (unsigned int)v[4] | ((unsigned int)v[5] << 16);
        q.w = (unsigned int)v[6] | ((unsigned int)v[7] << 16);
        const int off = (((t * 32 + j) * 128) + c8 * 16) ^ ((j & 7) << 4);
        *(uint4*)(ws + off) = q;
    }

    f32x4 acc[2][2] = {};
    const int w0 = wv * 32;

    for (int ty = 0; ty < 3; ++ty) {
        const int hy = h - 1 + ty;
        const bool vrow = (hy >= 0) && (hy < HH);
        __syncthreads();
        if (vrow) {
            const float* src = xrow0 + (size_t)hy * WW * CIN;
            #pragma unroll
            for (int r = 0; r < 4; ++r) {
                const int ch = tid + 256 * r;
                const int c8 = ch & 7;
                const int w  = ch >> 3;
                const float* p = src + (size_t)w * CIN + c8 * 8;
                float4 a0 = *(const float4*)p;
                float4 a1 = *(const float4*)(p + 4);
                uint4 q;
                q.x = (unsigned int)f2bf(a0.x) | ((unsigned int)f2bf(a0.y) << 16);
                q.y = (unsigned int)f2bf(a0.z) | ((unsigned int)f2bf(a0.w) << 16);
                q.z = (unsigned int)f2bf(a1.x) | ((unsigned int)f2bf(a1.y) << 16);
                q.w = (unsigned int)f2bf(a1.z) | ((unsigned int)f2bf(a1.w) << 16);
                const int off = (w * 128 + c8 * 16) ^ ((w & 7) << 4);
                *(uint4*)(xs + off) = q;
            }
        }
        __syncthreads();
        if (!vrow) continue;

        #pragma unroll
        for (int tx = 0; tx < 3; ++tx) {
            const int t = ty * 3 + tx;
            #pragma unroll
            for (int ch2 = 0; ch2 < 2; ++ch2) {
                bf16x8 bfr[2];
                #pragma unroll
                for (int nf = 0; nf < 2; ++nf) {
                    const int j = nf * 16 + (lane & 15);
                    const int off = (((t * 32 + j) * 128) + ch2 * 64 + ((lane >> 4) * 16))
                                    ^ ((j & 7) << 4);
                    bfr[nf] = *(const bf16x8*)(ws + off);
                }
                bf16x8 afr[2];
                #pragma unroll
                for (int m = 0; m < 2; ++m) {
                    const int wp = w0 + m * 16 + (lane & 15) + tx - 1;
                    const bool vv = (wp >= 0) && (wp < WW);
                    const int wc = vv ? wp : 0;
                    const int off = (wc * 128 + ch2 * 64 + ((lane >> 4) * 16))
                                    ^ ((wc & 7) << 4);
                    bf16x8 a = *(const bf16x8*)(xs + off);
                    if (!vv) a = (bf16x8)(short)0;
                    afr[m] = a;
                }
                acc[0][0] = __builtin_amdgcn_mfma_f32_16x16x32_bf16(afr[0], bfr[0], acc[0][0], 0, 0, 0);
                acc[0][1] = __builtin_amdgcn_mfma_f32_16x16x32_bf16(afr[0], bfr[1], acc[0][1], 0, 0, 0);
                acc[1][0] = __builtin_amdgcn_mfma_f32_16x16x32_bf16(afr[1], bfr[0], acc[1][0], 0, 0, 0);
                acc[1][1] = __builtin_amdgcn_mfma_f32_16x16x32_bf16(afr[1], bfr[1], acc[1][1], 0, 0, 0);
            }
        }
    }

    // ---- store: D col = lane&15 (j), row = 4*(lane>>4)+reg (m89-verified) ----
    const int pixbase = (b * HH + h) * WW;
    #pragma unroll
    for (int nf = 0; nf < 2; ++nf) {
        const int j = nf * 16 + (lane & 15);
        if (j >= OMC) continue;
        const float bb = bofs[j];
        #pragma unroll
        for (int m = 0; m < 2; ++m) {
            const int row0 = w0 + m * 16 + ((lane >> 4) * 4);
            #pragma unroll
            for (int r = 0; r < 4; ++r) {
                om[(size_t)(pixbase + row0 + r) * OMC + j] = acc[m][nf][r] + bb;
            }
        }
    }
}

// ---------------------------------------------------------------------------
// Kernel 2: deformable sampling + 576->64 contraction (unchanged this round).
// ---------------------------------------------------------------------------
#define PPW 8
#define WAVES 2

__global__ __launch_bounds__(WAVES * 64) void dcn_main_kernel(
    const float* __restrict__ x,
    const float* __restrict__ wmain,   // [9][64][64] = [tc][o]
    const float* __restrict__ bias,
    const float* __restrict__ om,
    float* __restrict__ out)
{
    __shared__ float s_s[WAVES * PPW * KK * CIN];

    const int lane = threadIdx.x & 63;
    const int wv   = threadIdx.x >> 6;
    const int pix0 = (blockIdx.x * WAVES + wv) * PPW;
    float* sbase = s_s + wv * (PPW * KK * CIN);

    for (int p = 0; p < PPW; ++p) {
        const int pix = pix0 + p;
        const int w = pix & (WW - 1);
        const int h = (pix >> 7) & (HH - 1);
        const int b = pix >> 14;
        const float* omp = om + (size_t)pix * OMC;
        const float* xb  = x + (size_t)b * HH * WW * CIN;

        #pragma unroll
        for (int t = 0; t < KK; ++t) {
            const float dy = omp[2 * t];
            const float dx = omp[2 * t + 1];
            float mk = omp[18 + t];
            mk = 1.0f / (1.0f + expf(-mk));

            const float py = (float)(h - 1 + (t / 3)) + dy;
            const float px = (float)(w - 1 + (t % 3)) + dx;
            const float fy = floorf(py), fx = floorf(px);
            const int y0 = (int)fy, x0 = (int)fx;
            const float wy1 = py - fy, wx1 = px - fx;
            const float wy0 = 1.0f - wy1, wx0 = 1.0f - wx1;

            float v = 0.0f;
            if (y0 >= 0 && y0 < HH) {
                const float* row = xb + (size_t)y0 * WW * CIN;
                if (x0 >= 0 && x0 < WW)
                    v = fmaf(wy0 * wx0, row[(size_t)x0 * CIN + lane], v);
                if (x0 + 1 >= 0 && x0 + 1 < WW)
                    v = fmaf(wy0 * wx1, row[(size_t)(x0 + 1) * CIN + lane], v);
            }
            if (y0 + 1 >= 0 && y0 + 1 < HH) {
                const float* row = xb + (size_t)(y0 + 1) * WW * CIN;
                if (x0 >= 0 && x0 < WW)
                    v = fmaf(wy1 * wx0, row[(size_t)x0 * CIN + lane], v);
                if (x0 + 1 >= 0 && x0 + 1 < WW)
                    v = fmaf(wy1 * wx1, row[(size_t)(x0 + 1) * CIN + lane], v);
            }
            sbase[(p * KK + t) * CIN + lane] = v * mk;
        }
    }
    __syncthreads();

    float acc[PPW];
    const float bs = bias[lane];
    #pragma unroll
    for (int p = 0; p < PPW; ++p) acc[p] = bs;

    for (int tc = 0; tc < KK * CIN; tc += 4) {
        const float w0 = wmain[(size_t)(tc + 0) * COUT + lane];
        const float w1 = wmain[(size_t)(tc + 1) * COUT + lane];
        const float w2 = wmain[(size_t)(tc + 2) * COUT + lane];
        const float w3 = wmain[(size_t)(tc + 3) * COUT + lane];
        #pragma unroll
        for (int p = 0; p < PPW; ++p) {
            const float4 sv = *reinterpret_cast<const float4*>(&sbase[p * (KK * CIN) + tc]);
            acc[p] = fmaf(sv.x, w0, acc[p]);
            acc[p] = fmaf(sv.y, w1, acc[p]);
            acc[p] = fmaf(sv.z, w2, acc[p]);
            acc[p] = fmaf(sv.w, w3, acc[p]);
        }
    }

    #pragma unroll
    for (int p = 0; p < PPW; ++p)
        out[(size_t)(pix0 + p) * COUT + lane] = acc[p];
}

extern "C" void kernel_launch(void* const* d_in, const int* in_sizes, int n_in,
                              void* d_out, int out_size, void* d_ws, size_t ws_size,
                              hipStream_t stream)
{
    const float* x     = (const float*)d_in[0];
    const float* wmain = (const float*)d_in[1];
    const float* bias  = (const float*)d_in[2];
    const float* wofs  = (const float*)d_in[3];
    const float* bofs  = (const float*)d_in[4];
    float* out = (float*)d_out;
    float* om  = (float*)d_ws;  // NPIX * 27 * 4 B = 6.75 MB

    {
        const int blocks = BB * HH;  // 512 blocks, one per image row
        offset_conv_mfma<<<blocks, 256, 0, stream>>>(x, wofs, bofs, om);
    }
    {
        const int blocks = NPIX / (WAVES * PPW);  // 4096
        dcn_main_kernel<<<blocks, WAVES * 64, 0, stream>>>(x, wmain, bias, om, out);
    }
}

// Round 3
// 157.174 us; speedup vs baseline: 4.5136x; 2.2145x over previous
//
#include <hip/hip_runtime.h>
#include <math.h>

#define BB 4
#define HH 128
#define WW 128
#define CIN 64
#define COUT 64
#define KK 9
#define OMC 27
#define NPIX (BB * HH * WW)

typedef __attribute__((ext_vector_type(8))) short bf16x8;
typedef __attribute__((ext_vector_type(4))) float f32x4;

static __device__ __forceinline__ unsigned short f2bf(float f) {
    unsigned int u = __float_as_uint(f);
    unsigned int r = (u + 0x7fffu + ((u >> 16) & 1u)) >> 16;
    return (unsigned short)r;
}

// ---------------------------------------------------------------------------
// Kernel 0: one-shot transform of wmain f32 [576 k][64 n] into bf16 MFMA
// B-frag-ready layout: frag (ks, nf) holds k = ks*32 + (lane>>4)*8 + j,
// n = nf*16 + (lane&15); stored at wb[(ks*4+nf)*64 + lane] as uint4 (8 bf16).
// Main kernel then loads B-frags as perfectly coalesced 16B/lane from L2.
// ---------------------------------------------------------------------------
__global__ __launch_bounds__(64) void wb_transform(
    const float* __restrict__ wmain, uint4* __restrict__ wb)
{
    const int tid  = blockIdx.x * 64 + threadIdx.x;  // [0, 18*4*64)
    const int lane = tid & 63;
    const int nf   = (tid >> 6) & 3;
    const int ks   = tid >> 8;
    const int k0   = ks * 32 + ((lane >> 4) * 8);
    const int n    = nf * 16 + (lane & 15);
    unsigned short v[8];
    #pragma unroll
    for (int j = 0; j < 8; ++j) v[j] = f2bf(wmain[(size_t)(k0 + j) * COUT + n]);
    uint4 q;
    q.x = (unsigned int)v[0] | ((unsigned int)v[1] << 16);
    q.y = (unsigned int)v[2] | ((unsigned int)v[3] << 16);
    q.z = (unsigned int)v[4] | ((unsigned int)v[5] << 16);
    q.w = (unsigned int)v[6] | ((unsigned int)v[7] << 16);
    wb[tid] = q;
}

// ---------------------------------------------------------------------------
// Kernel 1: offset/mask conv as bf16 MFMA implicit GEMM (unchanged from R1,
// plus XCD-chunked block swizzle).
// ---------------------------------------------------------------------------
__global__ __launch_bounds__(256) void offset_conv_mfma(
    const float* __restrict__ x,
    const float* __restrict__ wofs,
    const float* __restrict__ bofs,
    float* __restrict__ om)
{
    __shared__ char lds[16384 + 36864];
    char* xs = lds;
    char* ws = lds + 16384;

    const int tid  = threadIdx.x;
    const int lane = tid & 63;
    const int wv   = tid >> 6;
    const int bid = ((blockIdx.x & 7) << 6) + (blockIdx.x >> 3);  // XCD chunk (512 = 8*64)
    const int b = bid >> 7;
    const int h = bid & (HH - 1);
    const float* xrow0 = x + (size_t)b * HH * WW * CIN;

    #pragma unroll
    for (int r = 0; r < 9; ++r) {
        const int t  = r;
        const int j  = (tid >> 3) & 31;
        const int c8 = tid & 7;
        unsigned short v[8];
        if (j < OMC) {
            const float* wp = wofs + ((size_t)t * CIN + c8 * 8) * OMC + j;
            #pragma unroll
            for (int i = 0; i < 8; ++i) v[i] = f2bf(wp[i * OMC]);
        } else {
            #pragma unroll
            for (int i = 0; i < 8; ++i) v[i] = 0;
        }
        uint4 q;
        q.x = (unsigned int)v[0] | ((unsigned int)v[1] << 16);
        q.y = (unsigned int)v[2] | ((unsigned int)v[3] << 16);
        q.z = (unsigned int)v[4] | ((unsigned int)v[5] << 16);
        q.w = (unsigned int)v[6] | ((unsigned int)v[7] << 16);
        const int off = (((t * 32 + j) * 128) + c8 * 16) ^ ((j & 7) << 4);
        *(uint4*)(ws + off) = q;
    }

    f32x4 acc[2][2] = {};
    const int w0 = wv * 32;

    for (int ty = 0; ty < 3; ++ty) {
        const int hy = h - 1 + ty;
        const bool vrow = (hy >= 0) && (hy < HH);
        __syncthreads();
        if (vrow) {
            const float* src = xrow0 + (size_t)hy * WW * CIN;
            #pragma unroll
            for (int r = 0; r < 4; ++r) {
                const int ch = tid + 256 * r;
                const int c8 = ch & 7;
                const int w  = ch >> 3;
                const float* p = src + (size_t)w * CIN + c8 * 8;
                float4 a0 = *(const float4*)p;
                float4 a1 = *(const float4*)(p + 4);
                uint4 q;
                q.x = (unsigned int)f2bf(a0.x) | ((unsigned int)f2bf(a0.y) << 16);
                q.y = (unsigned int)f2bf(a0.z) | ((unsigned int)f2bf(a0.w) << 16);
                q.z = (unsigned int)f2bf(a1.x) | ((unsigned int)f2bf(a1.y) << 16);
                q.w = (unsigned int)f2bf(a1.z) | ((unsigned int)f2bf(a1.w) << 16);
                const int off = (w * 128 + c8 * 16) ^ ((w & 7) << 4);
                *(uint4*)(xs + off) = q;
            }
        }
        __syncthreads();
        if (!vrow) continue;

        #pragma unroll
        for (int tx = 0; tx < 3; ++tx) {
            const int t = ty * 3 + tx;
            #pragma unroll
            for (int ch2 = 0; ch2 < 2; ++ch2) {
                bf16x8 bfr[2];
                #pragma unroll
                for (int nf = 0; nf < 2; ++nf) {
                    const int j = nf * 16 + (lane & 15);
                    const int off = (((t * 32 + j) * 128) + ch2 * 64 + ((lane >> 4) * 16))
                                    ^ ((j & 7) << 4);
                    bfr[nf] = *(const bf16x8*)(ws + off);
                }
                bf16x8 afr[2];
                #pragma unroll
                for (int m = 0; m < 2; ++m) {
                    const int wp = w0 + m * 16 + (lane & 15) + tx - 1;
                    const bool vv = (wp >= 0) && (wp < WW);
                    const int wc = vv ? wp : 0;
                    const int off = (wc * 128 + ch2 * 64 + ((lane >> 4) * 16))
                                    ^ ((wc & 7) << 4);
                    bf16x8 a = *(const bf16x8*)(xs + off);
                    if (!vv) a = (bf16x8)(short)0;
                    afr[m] = a;
                }
                acc[0][0] = __builtin_amdgcn_mfma_f32_16x16x32_bf16(afr[0], bfr[0], acc[0][0], 0, 0, 0);
                acc[0][1] = __builtin_amdgcn_mfma_f32_16x16x32_bf16(afr[0], bfr[1], acc[0][1], 0, 0, 0);
                acc[1][0] = __builtin_amdgcn_mfma_f32_16x16x32_bf16(afr[1], bfr[0], acc[1][0], 0, 0, 0);
                acc[1][1] = __builtin_amdgcn_mfma_f32_16x16x32_bf16(afr[1], bfr[1], acc[1][1], 0, 0, 0);
            }
        }
    }

    const int pixbase = (b * HH + h) * WW;
    #pragma unroll
    for (int nf = 0; nf < 2; ++nf) {
        const int j = nf * 16 + (lane & 15);
        if (j >= OMC) continue;
        const float bb = bofs[j];
        #pragma unroll
        for (int m = 0; m < 2; ++m) {
            const int row0 = w0 + m * 16 + ((lane >> 4) * 4);
            #pragma unroll
            for (int r = 0; r < 4; ++r) {
                om[(size_t)(pixbase + row0 + r) * OMC + j] = acc[m][nf][r] + bb;
            }
        }
    }
}

// ---------------------------------------------------------------------------
// Kernel 2: deformable sampling + MFMA contraction.
// Block = 256 thr = 4 waves, TM = 64 pixels (same image row), wave owns 16 px.
// Gather: half-wave per (pixel,tap), 2 channels/lane, bilinear f32, pack
//         2xbf16, ds_write_b32 into XOR-swizzled s_tile[64][576].
// No __syncthreads: each wave reads only the rows it wrote.
// MFMA:   A-frag from LDS (swizzled), B-frag streamed from wb (L2), 72 MFMA.
// ---------------------------------------------------------------------------
#define TM 64

__global__ __launch_bounds__(256) void dcn_main_mfma(
    const float* __restrict__ x,
    const uint4* __restrict__ wb,
    const float* __restrict__ bias,
    const float* __restrict__ om,
    float* __restrict__ out)
{
    __shared__ char s_tile[TM * 1152];  // 64 px * 576 k * 2B = 73728

    const int tid  = threadIdx.x;
    const int lane = tid & 63;
    const int wv   = tid >> 6;
    const int bid  = ((blockIdx.x & 7) << 7) + (blockIdx.x >> 3);  // 1024 = 8*128
    const int pix0 = bid * TM;
    const int b    = pix0 >> 14;
    const int h    = (pix0 >> 7) & (HH - 1);
    const int w0   = pix0 & (WW - 1);
    const float* xb = x + (size_t)b * HH * WW * CIN;

    const int half = lane >> 5;
    const int c0   = (lane & 31) * 2;

    #pragma unroll 4
    for (int it = 0; it < 72; ++it) {
        const int pa = it * 2 + half;            // [0,144)
        const int pl = (pa * 7282) >> 16;        // pa / 9
        const int t  = pa - pl * 9;
        const int p  = wv * 16 + pl;
        const int pix = pix0 + p;
        const float* omp = om + (size_t)pix * OMC;
        const float dy = omp[2 * t];
        const float dx = omp[2 * t + 1];
        const float mk = 1.0f / (1.0f + __expf(-omp[18 + t]));

        const int ty = (t * 11) >> 5;            // t / 3
        const int tx = t - ty * 3;
        const float py  = (float)(h - 1 + ty) + dy;
        const float pxx = (float)(w0 + p - 1 + tx) + dx;
        const float fy = floorf(py), fx = floorf(pxx);
        const int y0 = (int)fy, x0 = (int)fx;
        const float wy1 = py - fy, wx1 = pxx - fx;
        const float wy0 = 1.0f - wy1, wx0 = 1.0f - wx1;

        float v0 = 0.0f, v1 = 0.0f;
        if ((unsigned)y0 < (unsigned)HH) {
            const float* row = xb + (size_t)y0 * WW * CIN;
            if ((unsigned)x0 < (unsigned)WW) {
                const float2 c = *(const float2*)(row + (size_t)x0 * CIN + c0);
                v0 = fmaf(wy0 * wx0, c.x, v0); v1 = fmaf(wy0 * wx0, c.y, v1);
            }
            if ((unsigned)(x0 + 1) < (unsigned)WW) {
                const float2 c = *(const float2*)(row + (size_t)(x0 + 1) * CIN + c0);
                v0 = fmaf(wy0 * wx1, c.x, v0); v1 = fmaf(wy0 * wx1, c.y, v1);
            }
        }
        if ((unsigned)(y0 + 1) < (unsigned)HH) {
            const float* row = xb + (size_t)(y0 + 1) * WW * CIN;
            if ((unsigned)x0 < (unsigned)WW) {
                const float2 c = *(const float2*)(row + (size_t)x0 * CIN + c0);
                v0 = fmaf(wy1 * wx0, c.x, v0); v1 = fmaf(wy1 * wx0, c.y, v1);
            }
            if ((unsigned)(x0 + 1) < (unsigned)WW) {
                const float2 c = *(const float2*)(row + (size_t)(x0 + 1) * CIN + c0);
                v0 = fmaf(wy1 * wx1, c.x, v0); v1 = fmaf(wy1 * wx1, c.y, v1);
            }
        }
        v0 *= mk; v1 *= mk;
        const unsigned int pk = (unsigned int)f2bf(v0) | ((unsigned int)f2bf(v1) << 16);
        const int off = (p * 1152 + (t * 64 + c0) * 2) ^ ((p & 7) << 4);
        *(unsigned int*)(s_tile + off) = pk;
    }

    // ---- MFMA: wave reads only its own 16 rows (no barrier needed) ----
    f32x4 acc[4] = {};
    const int mrow = wv * 16 + (lane & 15);
    const int abase = mrow * 1152 + ((lane >> 4) * 16);
    const int swz = (mrow & 7) << 4;

    #pragma unroll 6
    for (int ks = 0; ks < 18; ++ks) {
        const bf16x8 a = *(const bf16x8*)(s_tile + ((abase + ks * 64) ^ swz));
        #pragma unroll
        for (int nf = 0; nf < 4; ++nf) {
            const bf16x8 bfr = *(const bf16x8*)(wb + (ks * 4 + nf) * 64 + lane);
            acc[nf] = __builtin_amdgcn_mfma_f32_16x16x32_bf16(a, bfr, acc[nf], 0, 0, 0);
        }
    }

    // D: col = lane&15 -> n (cout), row = 4*(lane>>4)+r -> m (pixel)
    #pragma unroll
    for (int nf = 0; nf < 4; ++nf) {
        const int n  = nf * 16 + (lane & 15);
        const float bs = bias[n];
        const int m0 = wv * 16 + ((lane >> 4) * 4);
        #pragma unroll
        for (int r = 0; r < 4; ++r) {
            out[(size_t)(pix0 + m0 + r) * COUT + n] = acc[nf][r] + bs;
        }
    }
}

extern "C" void kernel_launch(void* const* d_in, const int* in_sizes, int n_in,
                              void* d_out, int out_size, void* d_ws, size_t ws_size,
                              hipStream_t stream)
{
    const float* x     = (const float*)d_in[0];
    const float* wmain = (const float*)d_in[1];
    const float* bias  = (const float*)d_in[2];
    const float* wofs  = (const float*)d_in[3];
    const float* bofs  = (const float*)d_in[4];
    float* out = (float*)d_out;
    float* om  = (float*)d_ws;                          // NPIX*27*4 = 7077888 B
    uint4* wb  = (uint4*)((char*)d_ws + (size_t)NPIX * OMC * 4);  // +73728 B

    wb_transform<<<72, 64, 0, stream>>>(wmain, wb);
    offset_conv_mfma<<<BB * HH, 256, 0, stream>>>(x, wofs, bofs, om);
    dcn_main_mfma<<<NPIX / TM, 256, 0, stream>>>(x, wb, bias, om, out);
}

// Round 4
// 82.876 us; speedup vs baseline: 8.5601x; 1.8965x over previous
//
#include <hip/hip_runtime.h>
#include <math.h>

#define BB 4
#define HH 128
#define WW 128
#define CIN 64
#define COUT 64
#define KK 9
#define OMC 27
#define NPIX (BB * HH * WW)

typedef __attribute__((ext_vector_type(8))) short bf16x8;
typedef __attribute__((ext_vector_type(4))) float f32x4;

static __device__ __forceinline__ unsigned short f2bf(float f) {
    unsigned int u = __float_as_uint(f);
    unsigned int r = (u + 0x7fffu + ((u >> 16) & 1u)) >> 16;
    return (unsigned short)r;
}

// ---------------------------------------------------------------------------
// Kernel 0: one-shot transform of wmain f32 [576 k][64 n] into bf16 MFMA
// B-frag-ready layout (16B/lane coalesced loads in the main kernel).
// ---------------------------------------------------------------------------
__global__ __launch_bounds__(64) void wb_transform(
    const float* __restrict__ wmain, uint4* __restrict__ wb)
{
    const int tid  = blockIdx.x * 64 + threadIdx.x;  // [0, 18*4*64)
    const int lane = tid & 63;
    const int nf   = (tid >> 6) & 3;
    const int ks   = tid >> 8;
    const int k0   = ks * 32 + ((lane >> 4) * 8);
    const int n    = nf * 16 + (lane & 15);
    unsigned short v[8];
    #pragma unroll
    for (int j = 0; j < 8; ++j) v[j] = f2bf(wmain[(size_t)(k0 + j) * COUT + n]);
    uint4 q;
    q.x = (unsigned int)v[0] | ((unsigned int)v[1] << 16);
    q.y = (unsigned int)v[2] | ((unsigned int)v[3] << 16);
    q.z = (unsigned int)v[4] | ((unsigned int)v[5] << 16);
    q.w = (unsigned int)v[6] | ((unsigned int)v[7] << 16);
    wb[tid] = q;
}

// ---------------------------------------------------------------------------
// Kernel 1: offset/mask conv as bf16 MFMA implicit GEMM.
// Epilogue now FUSES the deformable-conv prep: for j<18 it adds the base
// sampling coordinate (absolute py/px), for j>=18 it applies sigmoid.
// ---------------------------------------------------------------------------
__global__ __launch_bounds__(256) void offset_conv_mfma(
    const float* __restrict__ x,
    const float* __restrict__ wofs,
    const float* __restrict__ bofs,
    float* __restrict__ om)
{
    __shared__ char lds[16384 + 36864];
    char* xs = lds;
    char* ws = lds + 16384;

    const int tid  = threadIdx.x;
    const int lane = tid & 63;
    const int wv   = tid >> 6;
    const int bid = ((blockIdx.x & 7) << 6) + (blockIdx.x >> 3);  // XCD chunk
    const int b = bid >> 7;
    const int h = bid & (HH - 1);
    const float* xrow0 = x + (size_t)b * HH * WW * CIN;

    #pragma unroll
    for (int r = 0; r < 9; ++r) {
        const int t  = r;
        const int j  = (tid >> 3) & 31;
        const int c8 = tid & 7;
        unsigned short v[8];
        if (j < OMC) {
            const float* wp = wofs + ((size_t)t * CIN + c8 * 8) * OMC + j;
            #pragma unroll
            for (int i = 0; i < 8; ++i) v[i] = f2bf(wp[i * OMC]);
        } else {
            #pragma unroll
            for (int i = 0; i < 8; ++i) v[i] = 0;
        }
        uint4 q;
        q.x = (unsigned int)v[0] | ((unsigned int)v[1] << 16);
        q.y = (unsigned int)v[2] | ((unsigned int)v[3] << 16);
        q.z = (unsigned int)v[4] | ((unsigned int)v[5] << 16);
        q.w = (unsigned int)v[6] | ((unsigned int)v[7] << 16);
        const int off = (((t * 32 + j) * 128) + c8 * 16) ^ ((j & 7) << 4);
        *(uint4*)(ws + off) = q;
    }

    f32x4 acc[2][2] = {};
    const int w0 = wv * 32;

    for (int ty = 0; ty < 3; ++ty) {
        const int hy = h - 1 + ty;
        const bool vrow = (hy >= 0) && (hy < HH);
        __syncthreads();
        if (vrow) {
            const float* src = xrow0 + (size_t)hy * WW * CIN;
            #pragma unroll
            for (int r = 0; r < 4; ++r) {
                const int ch = tid + 256 * r;
                const int c8 = ch & 7;
                const int w  = ch >> 3;
                const float* p = src + (size_t)w * CIN + c8 * 8;
                float4 a0 = *(const float4*)p;
                float4 a1 = *(const float4*)(p + 4);
                uint4 q;
                q.x = (unsigned int)f2bf(a0.x) | ((unsigned int)f2bf(a0.y) << 16);
                q.y = (unsigned int)f2bf(a0.z) | ((unsigned int)f2bf(a0.w) << 16);
                q.z = (unsigned int)f2bf(a1.x) | ((unsigned int)f2bf(a1.y) << 16);
                q.w = (unsigned int)f2bf(a1.z) | ((unsigned int)f2bf(a1.w) << 16);
                const int off = (w * 128 + c8 * 16) ^ ((w & 7) << 4);
                *(uint4*)(xs + off) = q;
            }
        }
        __syncthreads();
        if (!vrow) continue;

        #pragma unroll
        for (int tx = 0; tx < 3; ++tx) {
            const int t = ty * 3 + tx;
            #pragma unroll
            for (int ch2 = 0; ch2 < 2; ++ch2) {
                bf16x8 bfr[2];
                #pragma unroll
                for (int nf = 0; nf < 2; ++nf) {
                    const int j = nf * 16 + (lane & 15);
                    const int off = (((t * 32 + j) * 128) + ch2 * 64 + ((lane >> 4) * 16))
                                    ^ ((j & 7) << 4);
                    bfr[nf] = *(const bf16x8*)(ws + off);
                }
                bf16x8 afr[2];
                #pragma unroll
                for (int m = 0; m < 2; ++m) {
                    const int wp = w0 + m * 16 + (lane & 15) + tx - 1;
                    const bool vv = (wp >= 0) && (wp < WW);
                    const int wc = vv ? wp : 0;
                    const int off = (wc * 128 + ch2 * 64 + ((lane >> 4) * 16))
                                    ^ ((wc & 7) << 4);
                    bf16x8 a = *(const bf16x8*)(xs + off);
                    if (!vv) a = (bf16x8)(short)0;
                    afr[m] = a;
                }
                acc[0][0] = __builtin_amdgcn_mfma_f32_16x16x32_bf16(afr[0], bfr[0], acc[0][0], 0, 0, 0);
                acc[0][1] = __builtin_amdgcn_mfma_f32_16x16x32_bf16(afr[0], bfr[1], acc[0][1], 0, 0, 0);
                acc[1][0] = __builtin_amdgcn_mfma_f32_16x16x32_bf16(afr[1], bfr[0], acc[1][0], 0, 0, 0);
                acc[1][1] = __builtin_amdgcn_mfma_f32_16x16x32_bf16(afr[1], bfr[1], acc[1][1], 0, 0, 0);
            }
        }
    }

    const int pixbase = (b * HH + h) * WW;
    #pragma unroll
    for (int nf = 0; nf < 2; ++nf) {
        const int j = nf * 16 + (lane & 15);
        if (j >= OMC) continue;
        const float bb = bofs[j];
        #pragma unroll
        for (int m = 0; m < 2; ++m) {
            const int row0 = w0 + m * 16 + ((lane >> 4) * 4);
            #pragma unroll
            for (int r = 0; r < 4; ++r) {
                float val = acc[m][nf][r] + bb;
                const int wpix = row0 + r;
                if (j < 18) {
                    const int t = j >> 1;
                    if ((j & 1) == 0) val += (float)(h - 1 + t / 3);     // absolute py
                    else              val += (float)(wpix - 1 + t % 3);  // absolute px
                } else {
                    val = 1.0f / (1.0f + __expf(-val));                  // sigmoid(mask)
                }
                om[(size_t)(pixbase + wpix) * OMC + j] = val;
            }
        }
    }
}

// ---------------------------------------------------------------------------
// Kernel 2: deformable sampling + MFMA, per-tap K-split pipeline.
// Block = 256 thr = 4 waves, 64 px; wave owns 16 contiguous px.
// Per wave: stage om slice (432 f32) to LDS once; then per tap t:
//   gather [16 px][64 ch] bf16 into 2KB swizzled wave-private tile
//   (half-wave per pixel, 2 ch/lane, absolute coords + pre-sigmoided mask),
//   then 2 K-steps x 4 N-frags MFMA (B streamed coalesced from wb/L2).
// LDS = 15.1 KB -> all 4 blocks/CU resident. No __syncthreads anywhere.
// ---------------------------------------------------------------------------
#define TM 64

__global__ __launch_bounds__(256) void dcn_main_mfma(
    const float* __restrict__ x,
    const uint4* __restrict__ wb,
    const float* __restrict__ bias,
    const float* __restrict__ om,
    float* __restrict__ out)
{
    __shared__ float om_s[4][432];   // 6912 B
    __shared__ char  ts[4][2048];    // 8192 B: [16 px][64 ch] bf16, XOR-swizzled

    const int tid  = threadIdx.x;
    const int lane = tid & 63;
    const int wv   = tid >> 6;
    const int bid  = ((blockIdx.x & 7) << 7) + (blockIdx.x >> 3);  // XCD chunk
    const int pix0 = bid * TM;
    const int b    = pix0 >> 14;
    const char* xbb = (const char*)(x + (size_t)b * HH * WW * CIN);

    // ---- stage this wave's om slice: 432 contiguous f32 ----
    float* omw = om_s[wv];
    {
        const float* og = om + (size_t)(pix0 + wv * 16) * OMC;
        #pragma unroll
        for (int i = 0; i < 7; ++i) {
            const int idx = i * 64 + lane;
            if (idx < 432) omw[idx] = og[idx];
        }
    }

    char* tsw = ts[wv];
    const int half = lane >> 5;
    const int c0   = (lane & 31) * 2;
    const char* xbc = xbb + c0 * 4;   // per-lane channel base

    f32x4 acc[4] = {};

    for (int t = 0; t < KK; ++t) {
        // ---- gather this tap for the wave's 16 pixels ----
        #pragma unroll
        for (int it = 0; it < 8; ++it) {
            const int pl = it * 2 + half;
            const float py  = omw[pl * OMC + 2 * t];
            const float pxx = omw[pl * OMC + 2 * t + 1];
            const float mk  = omw[pl * OMC + 18 + t];

            const float fy = floorf(py), fx = floorf(pxx);
            const int y0 = (int)fy, x0 = (int)fx;
            const float wy1 = py - fy, wx1 = pxx - fx;
            const float wy0 = 1.0f - wy1, wx0 = 1.0f - wx1;

            float v0 = 0.0f, v1 = 0.0f;
            const bool vy0 = (unsigned)y0 < (unsigned)HH;
            const bool vy1 = (unsigned)(y0 + 1) < (unsigned)HH;
            const bool vx0 = (unsigned)x0 < (unsigned)WW;
            const bool vx1 = (unsigned)(x0 + 1) < (unsigned)WW;
            const int r0 = y0 * (WW * CIN * 4) + x0 * (CIN * 4);

            if (vy0) {
                if (vx0) {
                    const float2 c = *(const float2*)(xbc + r0);
                    v0 = fmaf(wy0 * wx0, c.x, v0); v1 = fmaf(wy0 * wx0, c.y, v1);
                }
                if (vx1) {
                    const float2 c = *(const float2*)(xbc + r0 + CIN * 4);
                    v0 = fmaf(wy0 * wx1, c.x, v0); v1 = fmaf(wy0 * wx1, c.y, v1);
                }
            }
            if (vy1) {
                if (vx0) {
                    const float2 c = *(const float2*)(xbc + r0 + WW * CIN * 4);
                    v0 = fmaf(wy1 * wx0, c.x, v0); v1 = fmaf(wy1 * wx0, c.y, v1);
                }
                if (vx1) {
                    const float2 c = *(const float2*)(xbc + r0 + WW * CIN * 4 + CIN * 4);
                    v0 = fmaf(wy1 * wx1, c.x, v0); v1 = fmaf(wy1 * wx1, c.y, v1);
                }
            }
            v0 *= mk; v1 *= mk;
            const unsigned int pk = (unsigned int)f2bf(v0) | ((unsigned int)f2bf(v1) << 16);
            const int off = (pl * 128 + c0 * 2) ^ ((pl & 7) << 4);
            *(unsigned int*)(tsw + off) = pk;
        }

        // ---- 2 K-steps of MFMA on the fresh tap tile ----
        const int arow = lane & 15;
        const int aswz = (arow & 7) << 4;
        #pragma unroll
        for (int ch2 = 0; ch2 < 2; ++ch2) {
            const bf16x8 a = *(const bf16x8*)(
                tsw + ((arow * 128 + ch2 * 64 + ((lane >> 4) * 16)) ^ aswz));
            const int ks = t * 2 + ch2;
            #pragma unroll
            for (int nf = 0; nf < 4; ++nf) {
                const bf16x8 bfr = *(const bf16x8*)(wb + (ks * 4 + nf) * 64 + lane);
                acc[nf] = __builtin_amdgcn_mfma_f32_16x16x32_bf16(a, bfr, acc[nf], 0, 0, 0);
            }
        }
    }

    // ---- epilogue: D col = lane&15 -> cout, row = 4*(lane>>4)+r -> pixel ----
    #pragma unroll
    for (int nf = 0; nf < 4; ++nf) {
        const int n  = nf * 16 + (lane & 15);
        const float bs = bias[n];
        const int m0 = wv * 16 + ((lane >> 4) * 4);
        #pragma unroll
        for (int r = 0; r < 4; ++r) {
            out[(size_t)(pix0 + m0 + r) * COUT + n] = acc[nf][r] + bs;
        }
    }
}

extern "C" void kernel_launch(void* const* d_in, const int* in_sizes, int n_in,
                              void* d_out, int out_size, void* d_ws, size_t ws_size,
                              hipStream_t stream)
{
    const float* x     = (const float*)d_in[0];
    const float* wmain = (const float*)d_in[1];
    const float* bias  = (const float*)d_in[2];
    const float* wofs  = (const float*)d_in[3];
    const float* bofs  = (const float*)d_in[4];
    float* out = (float*)d_out;
    float* om  = (float*)d_ws;                                    // 7077888 B
    uint4* wb  = (uint4*)((char*)d_ws + (size_t)NPIX * OMC * 4);  // +73728 B

    wb_transform<<<72, 64, 0, stream>>>(wmain, wb);
    offset_conv_mfma<<<BB * HH, 256, 0, stream>>>(x, wofs, bofs, om);
    dcn_main_mfma<<<NPIX / TM, 256, 0, stream>>>(x, wb, bias, om, out);
}